// Round 3
// baseline (1081.237 us; speedup 1.0000x reference)
//
#include <hip/hip_runtime.h>
#include <math.h>

#define HW      65536     // 256*256
#define NCH     64        // C
#define HIDDEN  128
#define NBATCH  32
#define NPIX    (NBATCH * HW)   // 2,097,152
#define NEG_FILL -1e9f

// -------------------------------------------------------------------------
// Kernel 1: per-pixel MLP  scores = W2 . relu(W1 f + b1) + b2, masked -> att
// Tile: 128 pixels x 128 hidden per block (256 threads), K = 64 channels.
// LDS: sF[64][128] feats + sW[64][128] W1^T = exactly 64 KB.
// Each thread: 8 pixels x 8 hidden register tile (64 fp32 acc regs).
// -------------------------------------------------------------------------
__global__ __launch_bounds__(256, 2) void mlp_att_kernel(
    const float* __restrict__ feat,   // (B, C, H, W)
    const float* __restrict__ W1,     // (HIDDEN, C) row-major
    const float* __restrict__ b1,     // (HIDDEN)
    const float* __restrict__ W2,     // (HIDDEN)
    const float* __restrict__ b2,     // scalar (1 elem)
    const int*   __restrict__ zone,   // (B, H, W)
    const int*   __restrict__ cats,   // (B)
    float*       __restrict__ att)    // (B, H, W) out: masked scores
{
    __shared__ __align__(16) float sF[NCH][128];   // sF[c][p]
    __shared__ __align__(16) float sW[NCH][128];   // sW[c][k] = W1[k][c]

    const int tid  = threadIdx.x;
    const int pix0 = blockIdx.x * 128;       // tile never crosses a batch (HW % 128 == 0)
    const int b    = pix0 >> 16;             // / HW
    const int hw0  = pix0 & (HW - 1);

    // ---- stage feats: 64 rows x 128 floats (2048 float4, 8 per thread) ----
    {
        const float* fbase = feat + (size_t)b * NCH * HW + hw0;
        #pragma unroll
        for (int r = 0; r < 8; ++r) {
            int idx = tid + r * 256;         // 0..2047
            int c   = idx >> 5;              // 32 float4 per row
            int p4  = idx & 31;
            float4 v = *(const float4*)(fbase + (size_t)c * HW + p4 * 4);
            *(float4*)&sF[c][p4 * 4] = v;
        }
    }
    // ---- stage W1 transposed: lanes walk k so LDS stores are conflict-free ----
    {
        #pragma unroll
        for (int r = 0; r < 8; ++r) {
            int idx = tid + r * 256;         // 0..2047
            int k   = idx & 127;
            int c4  = idx >> 7;              // 0..15
            float4 v = *(const float4*)(W1 + k * NCH + c4 * 4);
            sW[c4 * 4 + 0][k] = v.x;
            sW[c4 * 4 + 1][k] = v.y;
            sW[c4 * 4 + 2][k] = v.z;
            sW[c4 * 4 + 3][k] = v.w;
        }
    }
    __syncthreads();

    const int tx = tid & 15;    // hidden group: k = tx*8 + j
    const int ty = tid >> 4;    // pixel group:  p = ty*8 + i

    float acc[8][8];
    #pragma unroll
    for (int i = 0; i < 8; ++i)
        #pragma unroll
        for (int j = 0; j < 8; ++j) acc[i][j] = 0.f;

    #pragma unroll 8
    for (int c = 0; c < NCH; ++c) {
        float a[8], w[8];
        *(float4*)&a[0] = *(const float4*)&sF[c][ty * 8];
        *(float4*)&a[4] = *(const float4*)&sF[c][ty * 8 + 4];
        *(float4*)&w[0] = *(const float4*)&sW[c][tx * 8];
        *(float4*)&w[4] = *(const float4*)&sW[c][tx * 8 + 4];
        #pragma unroll
        for (int i = 0; i < 8; ++i)
            #pragma unroll
            for (int j = 0; j < 8; ++j)
                acc[i][j] = fmaf(a[i], w[j], acc[i][j]);
    }

    // ---- epilogue: relu(acc + b1) dot W2, reduce over the 16 tx lanes ----
    float b1v[8], w2v[8];
    #pragma unroll
    for (int j = 0; j < 8; ++j) {
        b1v[j] = b1[tx * 8 + j];
        w2v[j] = W2[tx * 8 + j];
    }
    float sp[8];
    #pragma unroll
    for (int i = 0; i < 8; ++i) {
        float s = 0.f;
        #pragma unroll
        for (int j = 0; j < 8; ++j) {
            float h = acc[i][j] + b1v[j];
            h = h > 0.f ? h : 0.f;
            s = fmaf(w2v[j], h, s);
        }
        sp[i] = s;
    }
    #pragma unroll
    for (int m = 1; m < 16; m <<= 1) {
        #pragma unroll
        for (int i = 0; i < 8; ++i) sp[i] += __shfl_xor(sp[i], m, 64);
    }

    if (tx == 0) {
        const float b2v  = b2[0];
        const int   catb = cats[b];
        const int*  zrow = zone + (size_t)b * HW + hw0 + ty * 8;
        float*      arow = att  + (size_t)b * HW + hw0 + ty * 8;
        #pragma unroll
        for (int i = 0; i < 8; ++i) {
            int  z = zrow[i];
            bool m = (z == catb) && (z > 0);
            arow[i] = m ? (sp[i] + b2v) : NEG_FILL;
        }
    }
}

// -------------------------------------------------------------------------
// Kernel 2: per-batch softmax stats (max, sum of exp). One block per batch.
// Also zero-inits the bag accumulator (ws is poisoned before every launch).
// -------------------------------------------------------------------------
__global__ __launch_bounds__(1024) void stats_kernel(
    const float* __restrict__ att,
    float* __restrict__ maxv, float* __restrict__ sumv, float* __restrict__ bag)
{
    __shared__ float red[16];
    __shared__ float smax;
    const int b   = blockIdx.x;
    const int tid = threadIdx.x;
    const float* a = att + (size_t)b * HW;

    float m = -3.4e38f;
    for (int i = tid; i < HW; i += 1024) m = fmaxf(m, a[i]);
    #pragma unroll
    for (int s = 1; s < 64; s <<= 1) m = fmaxf(m, __shfl_xor(m, s, 64));
    if ((tid & 63) == 0) red[tid >> 6] = m;
    __syncthreads();
    if (tid == 0) {
        float mm = red[0];
        #pragma unroll
        for (int i = 1; i < 16; ++i) mm = fmaxf(mm, red[i]);
        smax = mm;
    }
    __syncthreads();
    const float mx = smax;

    float s = 0.f;
    for (int i = tid; i < HW; i += 1024) s += expf(a[i] - mx);
    #pragma unroll
    for (int t = 1; t < 64; t <<= 1) s += __shfl_xor(s, t, 64);
    __syncthreads();                 // red[] reuse
    if ((tid & 63) == 0) red[tid >> 6] = s;
    __syncthreads();
    if (tid == 0) {
        float ss = 0.f;
        #pragma unroll
        for (int i = 0; i < 16; ++i) ss += red[i];
        maxv[b] = mx;
        sumv[b] = ss;
        bag[b]  = 0.f;
    }
}

// -------------------------------------------------------------------------
// Kernel 3: weights = exp(att-max)/sum (gated by has), bag += logit*weight.
// att buffer (d_out+1) is rewritten in place with the weights.
// One thread per element; each 256-thread block spans a single batch.
// -------------------------------------------------------------------------
__global__ __launch_bounds__(256) void finalize_kernel(
    float* __restrict__ att,              // in: scores, out: weights
    const float* __restrict__ logits,     // (B,1,H,W) flat
    const float* __restrict__ maxv, const float* __restrict__ sumv,
    float* __restrict__ bag)
{
    const int idx = blockIdx.x * 256 + threadIdx.x;
    const int b   = idx >> 16;
    const float mx  = maxv[b];
    const bool  has = mx > -5e8f;         // any unmasked pixel?
    const float inv = 1.f / sumv[b];

    const float a = att[idx];
    // masked positions: a == -1e9 -> expf underflows to exactly 0 (matches ref)
    const float w = has ? expf(a - mx) * inv : 0.f;
    att[idx] = w;

    float part = w * logits[idx];
    #pragma unroll
    for (int s = 1; s < 64; s <<= 1) part += __shfl_xor(part, s, 64);
    __shared__ float r[4];
    if ((threadIdx.x & 63) == 0) r[threadIdx.x >> 6] = part;
    __syncthreads();
    if (threadIdx.x == 0) atomicAdd(&bag[b], r[0] + r[1] + r[2] + r[3]);
}

// -------------------------------------------------------------------------
// Kernel 4: BCE-with-logits mean over batch -> d_out[0]
// -------------------------------------------------------------------------
__global__ __launch_bounds__(64) void loss_kernel(
    const float* __restrict__ bag, const float* __restrict__ labels,
    float* __restrict__ out)
{
    const int t = threadIdx.x;
    float l = 0.f;
    if (t < NBATCH) {
        float x = bag[t], y = labels[t];
        l = fmaxf(x, 0.f) - x * y + log1pf(expf(-fabsf(x)));
    }
    #pragma unroll
    for (int s = 1; s < 64; s <<= 1) l += __shfl_xor(l, s, 64);
    if (t == 0) out[0] = l * (1.f / NBATCH);
}

extern "C" void kernel_launch(void* const* d_in, const int* in_sizes, int n_in,
                              void* d_out, int out_size, void* d_ws, size_t ws_size,
                              hipStream_t stream)
{
    const float* logits = (const float*)d_in[0];  // (32,1,256,256)
    const float* feat   = (const float*)d_in[1];  // (32,64,256,256)
    const int*   zone   = (const int*)  d_in[2];  // (32,256,256)
    const int*   cats   = (const int*)  d_in[3];  // (32,)
    const float* labels = (const float*)d_in[4];  // (32,)
    const float* W1     = (const float*)d_in[5];  // (128,64)
    const float* b1v    = (const float*)d_in[6];  // (128,)
    const float* W2     = (const float*)d_in[7];  // (128,)
    const float* b2v    = (const float*)d_in[8];  // scalar

    float* out = (float*)d_out;       // [0] = loss, [1..] = attention_maps
    float* att = out + 1;             // reuse output buffer as score scratch

    float* wsf  = (float*)d_ws;       // tiny stats scratch (384 B)
    float* maxv = wsf;
    float* sumv = wsf + 32;
    float* bag  = wsf + 64;

    mlp_att_kernel <<<NPIX / 128, 256, 0, stream>>>(feat, W1, b1v, W2, b2v, zone, cats, att);
    stats_kernel   <<<NBATCH, 1024, 0, stream>>>(att, maxv, sumv, bag);
    finalize_kernel<<<NPIX / 256, 256, 0, stream>>>(att, logits, maxv, sumv, bag);
    loss_kernel    <<<1, 64, 0, stream>>>(bag, labels, out);
}